// Round 1
// baseline (351.093 us; speedup 1.0000x reference)
//
#include <hip/hip_runtime.h>
#include <math.h>

#define B_ 8
#define S_ 2048
#define D_ 1024
#define H_ 64
#define BS_ (B_ * S_)          // 16384 rows

// ---------------------------------------------------------------------------
// Kernel 1: QKV projection.  qkv[3][BS][64] = x[BS][1024] @ {Wq,Wk,Wv}[1024][64]
// Block: 256 threads = 16x16, tile 64 rows x 64 cols, 4x4 register tiling.
// Grid: (BS/64) * 3 = 768 blocks.
// ---------------------------------------------------------------------------
__global__ __launch_bounds__(256) void qkv_proj(
    const float* __restrict__ x,
    const float* __restrict__ Wq,
    const float* __restrict__ Wk,
    const float* __restrict__ Wv,
    float* __restrict__ qkv)
{
    const int bid  = blockIdx.x;
    const int rb   = bid / 3;          // row block (0..255)
    const int wsel = bid % 3;          // 0=Q 1=K 2=V
    const float* __restrict__ W = (wsel == 0) ? Wq : ((wsel == 1) ? Wk : Wv);
    float* __restrict__ out = qkv + (size_t)wsel * BS_ * H_;

    const int t  = threadIdx.x;
    const int tx = t & 15;             // col group (4 cols)
    const int ty = t >> 4;             // row group (4 rows)
    const int row0 = rb * 64;

    // x tile stored transposed [k][row] so row-direction float4 reads work.
    __shared__ float xs[32][68];       // pad 68: 272B row stride, 16B aligned
    __shared__ float wsh[32][64];

    float acc[4][4] = {{0.f,0.f,0.f,0.f},{0.f,0.f,0.f,0.f},
                       {0.f,0.f,0.f,0.f},{0.f,0.f,0.f,0.f}};

    for (int k0 = 0; k0 < D_; k0 += 32) {
        // stage x: 64 rows x 32 k  (512 float4, 2 per thread)
        #pragma unroll
        for (int i = 0; i < 2; ++i) {
            int f = t + i * 256;
            int r = f >> 3;            // 0..63
            int kv = f & 7;            // float4 index along k
            float4 v = *(const float4*)&x[(size_t)(row0 + r) * D_ + k0 + kv * 4];
            xs[kv * 4 + 0][r] = v.x;
            xs[kv * 4 + 1][r] = v.y;
            xs[kv * 4 + 2][r] = v.z;
            xs[kv * 4 + 3][r] = v.w;
        }
        // stage W: 32 k x 64 c
        #pragma unroll
        for (int i = 0; i < 2; ++i) {
            int f = t + i * 256;
            int k  = f >> 4;           // 0..31
            int cv = f & 15;           // float4 index along c
            *(float4*)&wsh[k][cv * 4] =
                *(const float4*)&W[(size_t)(k0 + k) * H_ + cv * 4];
        }
        __syncthreads();

        #pragma unroll
        for (int k = 0; k < 32; ++k) {
            float4 a = *(const float4*)&xs[k][ty * 4];
            float4 b = *(const float4*)&wsh[k][tx * 4];
            acc[0][0] += a.x * b.x; acc[0][1] += a.x * b.y;
            acc[0][2] += a.x * b.z; acc[0][3] += a.x * b.w;
            acc[1][0] += a.y * b.x; acc[1][1] += a.y * b.y;
            acc[1][2] += a.y * b.z; acc[1][3] += a.y * b.w;
            acc[2][0] += a.z * b.x; acc[2][1] += a.z * b.y;
            acc[2][2] += a.z * b.z; acc[2][3] += a.z * b.w;
            acc[3][0] += a.w * b.x; acc[3][1] += a.w * b.y;
            acc[3][2] += a.w * b.z; acc[3][3] += a.w * b.w;
        }
        __syncthreads();
    }

    #pragma unroll
    for (int i = 0; i < 4; ++i) {
        float4 v = make_float4(acc[i][0], acc[i][1], acc[i][2], acc[i][3]);
        *(float4*)&out[(size_t)(row0 + ty * 4 + i) * H_ + tx * 4] = v;
    }
}

// ---------------------------------------------------------------------------
// Kernel 2: causal flash attention, fp32.
// One block = one (batch, 32-query tile). Grid = 8 * 64 = 512, heavy first.
// Per k-tile (32 keys): stage K/V in LDS, 2x2-tiled QK^T -> Ss, 8-lane-group
// online softmax, P*V accumulated in registers (8 head dims / thread).
// ---------------------------------------------------------------------------
__global__ __launch_bounds__(256) void attn(
    const float* __restrict__ qkv,
    float* __restrict__ outp)
{
    const int bi = blockIdx.x;
    const int tq = 63 - (bi >> 3);     // q-tile index, heaviest (63) first
    const int b  = bi & 7;

    const float* __restrict__ Q = qkv + (size_t)b * S_ * H_;
    const float* __restrict__ K = qkv + (size_t)BS_ * H_ + (size_t)b * S_ * H_;
    const float* __restrict__ V = qkv + (size_t)2 * BS_ * H_ + (size_t)b * S_ * H_;

    const int t = threadIdx.x;
    const int q0 = tq * 32;

    __shared__ float Qs[32][68];
    __shared__ float Ks[32][68];
    __shared__ float Vs[32][68];
    __shared__ float Ss[32][36];       // 144B row stride, 16B aligned

    // stage Q tile, pre-scaled by 1/sqrt(64)
    #pragma unroll
    for (int i = 0; i < 2; ++i) {
        int f = t + i * 256;
        int r = f >> 4;
        int c = (f & 15) * 4;
        float4 v = *(const float4*)&Q[(size_t)(q0 + r) * H_ + c];
        v.x *= 0.125f; v.y *= 0.125f; v.z *= 0.125f; v.w *= 0.125f;
        *(float4*)&Qs[r][c] = v;
    }

    // phase-1 mapping (2x2 score tile)
    const int sqi = (t & 15) * 2;      // q rows sqi, sqi+1
    const int ski = (t >> 4) * 2;      // k cols ski, ski+1
    // phase-2/3 mapping
    const int qr = t >> 3;             // q row 0..31
    const int hg = t & 7;              // head-dim group: dims hg*8..hg*8+7

    float o[8] = {0.f,0.f,0.f,0.f,0.f,0.f,0.f,0.f};
    float m = -INFINITY;
    float l = 0.f;

    for (int kt = 0; kt <= tq; ++kt) {
        __syncthreads();               // prior-iter phase3 done with Ks/Vs/Ss
        const int k0 = kt * 32;
        #pragma unroll
        for (int i = 0; i < 2; ++i) {
            int f = t + i * 256;
            int r = f >> 4;
            int c = (f & 15) * 4;
            *(float4*)&Ks[r][c] = *(const float4*)&K[(size_t)(k0 + r) * H_ + c];
            *(float4*)&Vs[r][c] = *(const float4*)&V[(size_t)(k0 + r) * H_ + c];
        }
        __syncthreads();

        // ---- phase 1: 2x2 scores over d=64
        float s00 = 0.f, s01 = 0.f, s10 = 0.f, s11 = 0.f;
        #pragma unroll
        for (int d = 0; d < 64; d += 4) {
            float4 a0 = *(const float4*)&Qs[sqi][d];
            float4 a1 = *(const float4*)&Qs[sqi + 1][d];
            float4 b0 = *(const float4*)&Ks[ski][d];
            float4 b1 = *(const float4*)&Ks[ski + 1][d];
            s00 += a0.x*b0.x + a0.y*b0.y + a0.z*b0.z + a0.w*b0.w;
            s01 += a0.x*b1.x + a0.y*b1.y + a0.z*b1.z + a0.w*b1.w;
            s10 += a1.x*b0.x + a1.y*b0.y + a1.z*b0.z + a1.w*b0.w;
            s11 += a1.x*b1.x + a1.y*b1.y + a1.z*b1.z + a1.w*b1.w;
        }
        if (kt == tq) {                // diagonal tile: mask k > q (q0 == k0)
            if (ski     > sqi    ) s00 = -INFINITY;
            if (ski + 1 > sqi    ) s01 = -INFINITY;
            if (ski     > sqi + 1) s10 = -INFINITY;
            if (ski + 1 > sqi + 1) s11 = -INFINITY;
        }
        Ss[sqi][ski]         = s00;
        Ss[sqi][ski + 1]     = s01;
        Ss[sqi + 1][ski]     = s10;
        Ss[sqi + 1][ski + 1] = s11;
        __syncthreads();

        // ---- phase 2: online softmax (8 lanes per row, 4 scores each)
        float4 sv = *(const float4*)&Ss[qr][hg * 4];
        float mx = fmaxf(fmaxf(sv.x, sv.y), fmaxf(sv.z, sv.w));
        mx = fmaxf(mx, __shfl_xor(mx, 1));
        mx = fmaxf(mx, __shfl_xor(mx, 2));
        mx = fmaxf(mx, __shfl_xor(mx, 4));
        float mnew  = fmaxf(m, mx);
        float alpha = __expf(m - mnew);    // first tile: exp(-inf)=0
        float4 p;
        p.x = __expf(sv.x - mnew);
        p.y = __expf(sv.y - mnew);
        p.z = __expf(sv.z - mnew);
        p.w = __expf(sv.w - mnew);
        float ps = p.x + p.y + p.z + p.w;
        ps += __shfl_xor(ps, 1);
        ps += __shfl_xor(ps, 2);
        ps += __shfl_xor(ps, 4);
        l = alpha * l + ps;
        m = mnew;
        #pragma unroll
        for (int j = 0; j < 8; ++j) o[j] *= alpha;
        *(float4*)&Ss[qr][hg * 4] = p;
        __syncthreads();

        // ---- phase 3: O += P * V
        #pragma unroll
        for (int k = 0; k < 32; ++k) {
            float pk = Ss[qr][k];
            float4 v0 = *(const float4*)&Vs[k][hg * 8];
            float4 v1 = *(const float4*)&Vs[k][hg * 8 + 4];
            o[0] += pk * v0.x; o[1] += pk * v0.y;
            o[2] += pk * v0.z; o[3] += pk * v0.w;
            o[4] += pk * v1.x; o[5] += pk * v1.y;
            o[6] += pk * v1.z; o[7] += pk * v1.w;
        }
    }

    const float inv = 1.0f / l;
    float4 r0 = make_float4(o[0]*inv, o[1]*inv, o[2]*inv, o[3]*inv);
    float4 r1 = make_float4(o[4]*inv, o[5]*inv, o[6]*inv, o[7]*inv);
    float* dst = outp + (size_t)(b * S_ + q0 + qr) * H_ + hg * 8;
    *(float4*)&dst[0] = r0;
    *(float4*)&dst[4] = r1;
}

// ---------------------------------------------------------------------------
extern "C" void kernel_launch(void* const* d_in, const int* in_sizes, int n_in,
                              void* d_out, int out_size, void* d_ws, size_t ws_size,
                              hipStream_t stream)
{
    const float* x  = (const float*)d_in[0];
    const float* Wq = (const float*)d_in[1];
    const float* Wk = (const float*)d_in[2];
    const float* Wv = (const float*)d_in[3];
    float* qkv = (float*)d_ws;                 // 3 * 16384 * 64 fp32 = 12 MB
    float* out = (float*)d_out;

    hipLaunchKernelGGL(qkv_proj, dim3((BS_ / 64) * 3), dim3(256), 0, stream,
                       x, Wq, Wk, Wv, qkv);
    hipLaunchKernelGGL(attn, dim3(B_ * (S_ / 32)), dim3(256), 0, stream,
                       qkv, out);
}

// Round 2
// 192.172 us; speedup vs baseline: 1.8270x; 1.8270x over previous
//
#include <hip/hip_runtime.h>
#include <math.h>

#define B_ 8
#define S_ 2048
#define D_ 1024
#define H_ 64
#define BS_ (B_ * S_)          // 16384 rows

typedef __attribute__((ext_vector_type(8))) short bf16x8;   // 8 bf16 = 4 VGPRs
typedef __attribute__((ext_vector_type(4))) float f32x4;

static __device__ __forceinline__ short f2bf(float f) {
    unsigned u = __builtin_bit_cast(unsigned, f);
    u = (u + 0x7fffu + ((u >> 16) & 1u)) >> 16;   // RTNE
    return (short)u;
}

// ---------------------------------------------------------------------------
// Kernel 0: W prep. Wt[3][64][1024] bf16 = W^T, with Wq pre-scaled by 0.125
// (folds the 1/sqrt(64) score scale into Q).
// ---------------------------------------------------------------------------
__global__ __launch_bounds__(256) void wprep(
    const float* __restrict__ Wq, const float* __restrict__ Wk,
    const float* __restrict__ Wv, short* __restrict__ Wt)
{
    const int o = blockIdx.x >> 6;
    const int n = blockIdx.x & 63;
    const float* __restrict__ W = (o == 0) ? Wq : ((o == 1) ? Wk : Wv);
    const float scale = (o == 0) ? 0.125f : 1.0f;
    for (int k = threadIdx.x; k < D_; k += 256)
        Wt[(size_t)(o * 64 + n) * D_ + k] = f2bf(W[(size_t)k * H_ + n] * scale);
}

// ---------------------------------------------------------------------------
// Kernel 1: QKV projection via bf16 MFMA.
// Block: 256 thr / 4 waves. Tile M=32 rows x N=192 cols (Q|K|V), BK=64.
// Wave w covers cols [w*48, w*48+48). Outputs: Qb,Kb row-major bf16,
// V written TRANSPOSED: Vt[b][64 d][2048 s] bf16.
// ---------------------------------------------------------------------------
__global__ __launch_bounds__(256) void qkv_proj(
    const float* __restrict__ x, const short* __restrict__ Wt,
    short* __restrict__ Qb, short* __restrict__ Kb, short* __restrict__ Vt)
{
    __shared__ short xs[32][72];     // pitch 72 (144B): 2-way-max frag reads
    __shared__ short wsh[192][72];

    const int t = threadIdx.x;
    const int w = t >> 6, lane = t & 63, col = lane & 15, quad = lane >> 4;
    const int row0 = blockIdx.x * 32;

    f32x4 acc[2][3] = {};
    const int arow = t >> 3;         // 0..31
    const int akk  = (t & 7) * 8;    // k chunk

    for (int k0 = 0; k0 < D_; k0 += 64) {
        // stage A: 32 rows x 64 k of x, fp32 -> bf16
        float4 f0 = *(const float4*)&x[(size_t)(row0 + arow) * D_ + k0 + akk];
        float4 f1 = *(const float4*)&x[(size_t)(row0 + arow) * D_ + k0 + akk + 4];
        bf16x8 av;
        av[0] = f2bf(f0.x); av[1] = f2bf(f0.y); av[2] = f2bf(f0.z); av[3] = f2bf(f0.w);
        av[4] = f2bf(f1.x); av[5] = f2bf(f1.y); av[6] = f2bf(f1.z); av[7] = f2bf(f1.w);
        *(bf16x8*)&xs[arow][akk] = av;
        // stage B: 192 rows x 64 k of Wt (bf16, flat [192][1024])
        #pragma unroll
        for (int i = 0; i < 6; ++i) {
            int idx = t + i * 256;
            int n = idx >> 3, kk = (idx & 7) * 8;
            *(bf16x8*)&wsh[n][kk] = *(const bf16x8*)&Wt[(size_t)n * D_ + k0 + kk];
        }
        __syncthreads();

        #pragma unroll
        for (int ks = 0; ks < 2; ++ks) {
            const int ka = ks * 32 + quad * 8;
            bf16x8 a0 = *(const bf16x8*)&xs[col][ka];
            bf16x8 a1 = *(const bf16x8*)&xs[16 + col][ka];
            #pragma unroll
            for (int nt = 0; nt < 3; ++nt) {
                bf16x8 bfr = *(const bf16x8*)&wsh[w * 48 + nt * 16 + col][ka];
                acc[0][nt] = __builtin_amdgcn_mfma_f32_16x16x32_bf16(a0, bfr, acc[0][nt], 0, 0, 0);
                acc[1][nt] = __builtin_amdgcn_mfma_f32_16x16x32_bf16(a1, bfr, acc[1][nt], 0, 0, 0);
            }
        }
        __syncthreads();
    }

    // epilogue: C layout col=lane&15, row=quad*4+reg
    #pragma unroll
    for (int mt = 0; mt < 2; ++mt)
    #pragma unroll
    for (int nt = 0; nt < 3; ++nt) {
        const int c = w * 48 + nt * 16 + col;
        const int o = c >> 6, cc = c & 63;
        #pragma unroll
        for (int r = 0; r < 4; ++r) {
            const int row = row0 + mt * 16 + quad * 4 + r;
            const short v = f2bf(acc[mt][nt][r]);
            if (o == 0)      Qb[(size_t)row * H_ + cc] = v;
            else if (o == 1) Kb[(size_t)row * H_ + cc] = v;
            else {
                const int b = row >> 11, s = row & 2047;
                Vt[(size_t)(b * 64 + cc) * S_ + s] = v;
            }
        }
    }
}

// ---------------------------------------------------------------------------
// Kernel 2: causal flash attention, bf16 MFMA, fp32 accumulate.
// Block: 32 q, 4 waves = (mtile 0/1) x (key-half 0/1). Wave owns 16 q rows,
// processes 64-key tiles kt = kh, kh+2, ... < nkt. NO barriers in k-loop.
// Q/K/V fragments read directly from global (L2-resident). P transposed
// C->A layout via wave-private LDS. Key-halves merged at the end via LDS.
// ---------------------------------------------------------------------------
__global__ __launch_bounds__(256) void attn(
    const short* __restrict__ Qb, const short* __restrict__ Kb,
    const short* __restrict__ Vt, float* __restrict__ outp)
{
    __shared__ short Ps[4][16][72];      // per-wave P tile (bf16)
    __shared__ float mO[2][16][68];      // key-half-1 partial O per mtile
    __shared__ float mml[2][2][16];      // [m|l][mtile][row]

    const int bi = blockIdx.x;
    const int j  = 63 - (bi >> 3);       // 32-q tile, heaviest first
    const int b  = bi & 7;
    const int t  = threadIdx.x;
    const int w = t >> 6, lane = t & 63, col = lane & 15, quad = lane >> 4;
    const int mt = w & 1, kh = w >> 1;
    const int q0 = j * 32, qbase = q0 + mt * 16;
    const int nkt = (j + 2) >> 1;        // ceil(32*(j+1)/64)

    // Q fragments in registers (A layout: m=lane&15, k=quad*8+j)
    const size_t qrow = (size_t)(b * S_ + qbase + col) * H_;
    const bf16x8 aq0 = *(const bf16x8*)&Qb[qrow + quad * 8];
    const bf16x8 aq1 = *(const bf16x8*)&Qb[qrow + 32 + quad * 8];

    f32x4 Oacc[4] = {};
    float m[4] = {-INFINITY, -INFINITY, -INFINITY, -INFINITY};
    float l[4] = {0.f, 0.f, 0.f, 0.f};

    const short* __restrict__ Kbb = Kb + (size_t)b * S_ * H_;
    const short* __restrict__ Vtb = Vt + (size_t)b * H_ * S_;

    for (int kt = kh; kt < nkt; kt += 2) {
        const int kbase = kt * 64;
        // ---- S = Q K^T (16q x 64k)
        f32x4 S[4] = {};
        #pragma unroll
        for (int nt = 0; nt < 4; ++nt) {
            const size_t krow = (size_t)(kbase + nt * 16 + col) * H_;
            bf16x8 bk0 = *(const bf16x8*)&Kbb[krow + quad * 8];
            bf16x8 bk1 = *(const bf16x8*)&Kbb[krow + 32 + quad * 8];
            S[nt] = __builtin_amdgcn_mfma_f32_16x16x32_bf16(aq0, bk0, S[nt], 0, 0, 0);
            S[nt] = __builtin_amdgcn_mfma_f32_16x16x32_bf16(aq1, bk1, S[nt], 0, 0, 0);
        }
        // ---- causal mask (only on diagonal-overlap tiles; wave-uniform)
        if (kbase + 63 > qbase) {
            #pragma unroll
            for (int nt = 0; nt < 4; ++nt) {
                const int key = kbase + nt * 16 + col;
                #pragma unroll
                for (int r = 0; r < 4; ++r) {
                    const int q = qbase + quad * 4 + r;
                    if (key > q) S[nt][r] = -INFINITY;
                }
            }
        }
        // ---- online softmax (row = quad*4+r; reduce over 16 cols via shfl)
        float alpha[4];
        #pragma unroll
        for (int r = 0; r < 4; ++r) {
            float mx = fmaxf(fmaxf(S[0][r], S[1][r]), fmaxf(S[2][r], S[3][r]));
            mx = fmaxf(mx, __shfl_xor(mx, 1));
            mx = fmaxf(mx, __shfl_xor(mx, 2));
            mx = fmaxf(mx, __shfl_xor(mx, 4));
            mx = fmaxf(mx, __shfl_xor(mx, 8));
            const float mn = fmaxf(m[r], mx);
            alpha[r] = __expf(m[r] - mn);      // first tile: exp(-inf)=0
            m[r] = mn;
            float rs = 0.f;
            #pragma unroll
            for (int nt = 0; nt < 4; ++nt) {
                const float p = __expf(S[nt][r] - mn);
                S[nt][r] = p;
                rs += p;
            }
            rs += __shfl_xor(rs, 1);
            rs += __shfl_xor(rs, 2);
            rs += __shfl_xor(rs, 4);
            rs += __shfl_xor(rs, 8);
            l[r] = l[r] * alpha[r] + rs;
        }
        #pragma unroll
        for (int nt = 0; nt < 4; ++nt)
            #pragma unroll
            for (int r = 0; r < 4; ++r) Oacc[nt][r] *= alpha[r];

        // ---- P: C layout -> bf16 -> wave-private LDS (transpose to A layout)
        #pragma unroll
        for (int nt = 0; nt < 4; ++nt)
            #pragma unroll
            for (int r = 0; r < 4; ++r)
                Ps[w][quad * 4 + r][nt * 16 + col] = f2bf(S[nt][r]);
        __asm__ volatile("s_waitcnt lgkmcnt(0)" ::: "memory");  // writes visible wave-wide

        // ---- O += P V  (V fragments straight from Vt global)
        #pragma unroll
        for (int ks = 0; ks < 2; ++ks) {
            bf16x8 ap = *(const bf16x8*)&Ps[w][col][ks * 32 + quad * 8];
            #pragma unroll
            for (int nt = 0; nt < 4; ++nt) {
                bf16x8 bv = *(const bf16x8*)
                    &Vtb[(size_t)(nt * 16 + col) * S_ + kbase + ks * 32 + quad * 8];
                Oacc[nt] = __builtin_amdgcn_mfma_f32_16x16x32_bf16(ap, bv, Oacc[nt], 0, 0, 0);
            }
        }
    }

    // ---- merge key-halves (kh=1 publishes; kh=0 combines and stores)
    __syncthreads();
    if (kh == 1) {
        #pragma unroll
        for (int nt = 0; nt < 4; ++nt)
            #pragma unroll
            for (int r = 0; r < 4; ++r)
                mO[mt][quad * 4 + r][nt * 16 + col] = Oacc[nt][r];
        if (col == 0) {
            #pragma unroll
            for (int r = 0; r < 4; ++r) {
                mml[0][mt][quad * 4 + r] = m[r];
                mml[1][mt][quad * 4 + r] = l[r];
            }
        }
    }
    __syncthreads();
    if (kh == 0) {
        #pragma unroll
        for (int r = 0; r < 4; ++r) {
            const int row = quad * 4 + r;
            const float m1 = mml[0][mt][row];
            const float l1 = mml[1][mt][row];
            const float ms = fmaxf(m[r], m1);
            const float a0 = __expf(m[r] - ms);
            const float a1 = __expf(m1 - ms);     // m1=-inf (no tiles) -> 0
            const float inv = 1.0f / (a0 * l[r] + a1 * l1);
            float* dst = outp + (size_t)(b * S_ + qbase + row) * H_;
            #pragma unroll
            for (int nt = 0; nt < 4; ++nt) {
                const float o = (a0 * Oacc[nt][r] + a1 * mO[mt][row][nt * 16 + col]) * inv;
                dst[nt * 16 + col] = o;
            }
        }
    }
}

// ---------------------------------------------------------------------------
extern "C" void kernel_launch(void* const* d_in, const int* in_sizes, int n_in,
                              void* d_out, int out_size, void* d_ws, size_t ws_size,
                              hipStream_t stream)
{
    const float* x  = (const float*)d_in[0];
    const float* Wq = (const float*)d_in[1];
    const float* Wk = (const float*)d_in[2];
    const float* Wv = (const float*)d_in[3];
    float* out = (float*)d_out;

    short* Qb = (short*)d_ws;            // [16384][64] bf16   (2 MB)
    short* Kb = Qb + (size_t)BS_ * H_;   // [16384][64] bf16   (2 MB)
    short* Vt = Kb + (size_t)BS_ * H_;   // [8][64][2048] bf16 (2 MB)
    short* Wt = Vt + (size_t)BS_ * H_;   // [3][64][1024] bf16 (384 KB)

    hipLaunchKernelGGL(wprep,    dim3(192), dim3(256), 0, stream, Wq, Wk, Wv, Wt);
    hipLaunchKernelGGL(qkv_proj, dim3(BS_ / 32), dim3(256), 0, stream, x, Wt, Qb, Kb, Vt);
    hipLaunchKernelGGL(attn,     dim3(B_ * (S_ / 32)), dim3(256), 0, stream, Qb, Kb, Vt, out);
}

// Round 3
// 157.806 us; speedup vs baseline: 2.2248x; 1.2178x over previous
//
#include <hip/hip_runtime.h>
#include <math.h>

#define B_ 8
#define S_ 2048
#define D_ 1024
#define H_ 64
#define BS_ (B_ * S_)          // 16384 rows

typedef __attribute__((ext_vector_type(8))) short bf16x8;   // 8 bf16 = 4 VGPRs
typedef __attribute__((ext_vector_type(4))) float f32x4;

static __device__ __forceinline__ short f2bf(float f) {
    unsigned u = __builtin_bit_cast(unsigned, f);
    u = (u + 0x7fffu + ((u >> 16) & 1u)) >> 16;   // RTNE
    return (short)u;
}

// ---------------------------------------------------------------------------
// Kernel 0: W prep, coalesced transpose via LDS.
// Wt[3][64][1024] bf16 = W^T;  Wq pre-scaled by 0.125*log2(e) so attention
// scores are in log2 domain (softmax uses native v_exp_f32 = exp2).
// Grid: 3 matrices x 16 k-slabs of 64 = 48 blocks.
// ---------------------------------------------------------------------------
__global__ __launch_bounds__(256) void wprep(
    const float* __restrict__ Wq, const float* __restrict__ Wk,
    const float* __restrict__ Wv, short* __restrict__ Wt)
{
    const int o  = blockIdx.x >> 4;        // 0..2
    const int k0 = (blockIdx.x & 15) * 64;
    const float* __restrict__ W = (o == 0) ? Wq : ((o == 1) ? Wk : Wv);
    const float scale = (o == 0) ? 0.125f * 1.44269504088896340736f : 1.0f;

    __shared__ float ls[64][65];
    const int r = threadIdx.x >> 6;        // 0..3
    const int c = threadIdx.x & 63;

    #pragma unroll
    for (int i = 0; i < 16; ++i)           // coalesced row-major read
        ls[i * 4 + r][c] = W[(size_t)(k0 + i * 4 + r) * H_ + c];
    __syncthreads();
    #pragma unroll
    for (int i = 0; i < 16; ++i) {         // coalesced row-major write of W^T
        const int n = i * 4 + r;
        Wt[(size_t)(o * 64 + n) * D_ + k0 + c] = f2bf(ls[c][n] * scale);
    }
}

// ---------------------------------------------------------------------------
// Kernel 1: QKV projection via bf16 MFMA, software-pipelined staging.
// Block: 256 thr / 4 waves. Tile M=32 x N=192 (Q|K|V), BK=64. Grid 512.
// Global loads for tile k0+64 are issued before the MFMA on tile k0 and
// stay in flight across the barrier (hides HBM latency behind compute).
// ---------------------------------------------------------------------------
__global__ __launch_bounds__(256) void qkv_proj(
    const float* __restrict__ x, const short* __restrict__ Wt,
    short* __restrict__ Qb, short* __restrict__ Kb, short* __restrict__ Vt)
{
    __shared__ short xs[32][72];     // pitch 72 shorts: 2-way-max frag reads
    __shared__ short wsh[192][72];

    const int t = threadIdx.x;
    const int w = t >> 6, lane = t & 63, col = lane & 15, quad = lane >> 4;
    const int row0 = blockIdx.x * 32;
    const int arow = t >> 3;         // 0..31
    const int akk  = (t & 7) * 8;    // k chunk (floats/shorts)

    f32x4 acc[2][3] = {};

    float4 xf0, xf1;
    bf16x8 wf[6];
    auto load_tile = [&](int k0) {
        xf0 = *(const float4*)&x[(size_t)(row0 + arow) * D_ + k0 + akk];
        xf1 = *(const float4*)&x[(size_t)(row0 + arow) * D_ + k0 + akk + 4];
        #pragma unroll
        for (int i = 0; i < 6; ++i) {
            const int idx = t + i * 256;
            wf[i] = *(const bf16x8*)&Wt[(size_t)(idx >> 3) * D_ + k0 + (idx & 7) * 8];
        }
    };

    load_tile(0);
    for (int k0 = 0; k0 < D_; k0 += 64) {
        // commit prefetched regs to LDS
        bf16x8 av;
        av[0] = f2bf(xf0.x); av[1] = f2bf(xf0.y); av[2] = f2bf(xf0.z); av[3] = f2bf(xf0.w);
        av[4] = f2bf(xf1.x); av[5] = f2bf(xf1.y); av[6] = f2bf(xf1.z); av[7] = f2bf(xf1.w);
        *(bf16x8*)&xs[arow][akk] = av;
        #pragma unroll
        for (int i = 0; i < 6; ++i) {
            const int idx = t + i * 256;
            *(bf16x8*)&wsh[idx >> 3][(idx & 7) * 8] = wf[i];
        }
        __syncthreads();
        if (k0 + 64 < D_) load_tile(k0 + 64);   // in flight during MFMA

        #pragma unroll
        for (int ks = 0; ks < 2; ++ks) {
            const int ka = ks * 32 + quad * 8;
            bf16x8 a0 = *(const bf16x8*)&xs[col][ka];
            bf16x8 a1 = *(const bf16x8*)&xs[16 + col][ka];
            #pragma unroll
            for (int nt = 0; nt < 3; ++nt) {
                bf16x8 bfr = *(const bf16x8*)&wsh[w * 48 + nt * 16 + col][ka];
                acc[0][nt] = __builtin_amdgcn_mfma_f32_16x16x32_bf16(a0, bfr, acc[0][nt], 0, 0, 0);
                acc[1][nt] = __builtin_amdgcn_mfma_f32_16x16x32_bf16(a1, bfr, acc[1][nt], 0, 0, 0);
            }
        }
        __syncthreads();
    }

    // epilogue: C layout col=lane&15, row=quad*4+reg
    #pragma unroll
    for (int mt = 0; mt < 2; ++mt)
    #pragma unroll
    for (int nt = 0; nt < 3; ++nt) {
        const int c = w * 48 + nt * 16 + col;
        const int o = c >> 6, cc = c & 63;
        #pragma unroll
        for (int r = 0; r < 4; ++r) {
            const int row = row0 + mt * 16 + quad * 4 + r;
            const short v = f2bf(acc[mt][nt][r]);
            if (o == 0)      Qb[(size_t)row * H_ + cc] = v;
            else if (o == 1) Kb[(size_t)row * H_ + cc] = v;
            else {
                const int b = row >> 11, s = row & 2047;
                Vt[(size_t)(b * 64 + cc) * S_ + s] = v;
            }
        }
    }
}

// ---------------------------------------------------------------------------
// Kernel 2: causal flash attention, bf16 MFMA, fp32 acc, log2-domain softmax.
// Block: 32 q, 4 waves = (mtile 0/1) x (key-half 0/1). No barriers in k-loop.
// K fragments register-double-buffered (prefetch kt+2 during kt); V loads
// issued right after the S-MFMA so softmax hides their latency.
// ---------------------------------------------------------------------------
__global__ __launch_bounds__(256) void attn(
    const short* __restrict__ Qb, const short* __restrict__ Kb,
    const short* __restrict__ Vt, float* __restrict__ outp)
{
    __shared__ short Ps[4][16][72];      // per-wave P tile (bf16)
    __shared__ float mO[2][16][68];      // key-half-1 partial O per mtile
    __shared__ float mml[2][2][16];      // [m|l][mtile][row]

    const int bi = blockIdx.x;
    const int j  = 63 - (bi >> 3);       // 32-q tile, heaviest first
    const int b  = bi & 7;
    const int t  = threadIdx.x;
    const int w = t >> 6, lane = t & 63, col = lane & 15, quad = lane >> 4;
    const int mt = w & 1, kh = w >> 1;
    const int q0 = j * 32, qbase = q0 + mt * 16;
    const int nkt = (j + 2) >> 1;        // ceil(32*(j+1)/64)

    // Q fragments (A layout: m=lane&15, k=quad*8+i)
    const size_t qrow = (size_t)(b * S_ + qbase + col) * H_;
    const bf16x8 aq0 = *(const bf16x8*)&Qb[qrow + quad * 8];
    const bf16x8 aq1 = *(const bf16x8*)&Qb[qrow + 32 + quad * 8];

    f32x4 Oacc[4] = {};
    float m[4] = {-INFINITY, -INFINITY, -INFINITY, -INFINITY};
    float l[4] = {0.f, 0.f, 0.f, 0.f};

    const short* __restrict__ Kbb = Kb + (size_t)b * S_ * H_;
    const short* __restrict__ Vtb = Vt + (size_t)b * H_ * S_;

    auto load_K = [&](bf16x8 (&dst)[4][2], int kb) {
        #pragma unroll
        for (int nt = 0; nt < 4; ++nt) {
            const size_t krow = (size_t)(kb + nt * 16 + col) * H_;
            dst[nt][0] = *(const bf16x8*)&Kbb[krow + quad * 8];
            dst[nt][1] = *(const bf16x8*)&Kbb[krow + 32 + quad * 8];
        }
    };

    bf16x8 kc[4][2], kn[4][2];
    if (kh < nkt) load_K(kc, kh * 64);

    for (int kt = kh; kt < nkt; kt += 2) {
        const int kbase = kt * 64;
        const bool more = (kt + 2) < nkt;
        if (more) load_K(kn, kbase + 128);     // prefetch next K tile

        // ---- S = Q K^T (16q x 64k) from register fragments
        f32x4 S[4] = {};
        #pragma unroll
        for (int nt = 0; nt < 4; ++nt) {
            S[nt] = __builtin_amdgcn_mfma_f32_16x16x32_bf16(aq0, kc[nt][0], S[nt], 0, 0, 0);
            S[nt] = __builtin_amdgcn_mfma_f32_16x16x32_bf16(aq1, kc[nt][1], S[nt], 0, 0, 0);
        }

        // ---- issue V loads now; softmax below hides their latency
        bf16x8 vv[2][4];
        #pragma unroll
        for (int ks = 0; ks < 2; ++ks)
            #pragma unroll
            for (int nt = 0; nt < 4; ++nt)
                vv[ks][nt] = *(const bf16x8*)
                    &Vtb[(size_t)(nt * 16 + col) * S_ + kbase + ks * 32 + quad * 8];

        // ---- causal mask (diagonal-overlap tiles only; wave-uniform branch)
        if (kbase + 63 > qbase) {
            #pragma unroll
            for (int nt = 0; nt < 4; ++nt) {
                const int key = kbase + nt * 16 + col;
                #pragma unroll
                for (int r = 0; r < 4; ++r)
                    if (key > qbase + quad * 4 + r) S[nt][r] = -INFINITY;
            }
        }

        // ---- online softmax, log2 domain (scores pre-scaled by log2(e))
        float alpha[4];
        #pragma unroll
        for (int r = 0; r < 4; ++r) {
            float mx = fmaxf(fmaxf(S[0][r], S[1][r]), fmaxf(S[2][r], S[3][r]));
            mx = fmaxf(mx, __shfl_xor(mx, 1));
            mx = fmaxf(mx, __shfl_xor(mx, 2));
            mx = fmaxf(mx, __shfl_xor(mx, 4));
            mx = fmaxf(mx, __shfl_xor(mx, 8));
            const float mn = fmaxf(m[r], mx);
            alpha[r] = __builtin_amdgcn_exp2f(m[r] - mn);   // first tile: 0
            m[r] = mn;
            float rs = 0.f;
            #pragma unroll
            for (int nt = 0; nt < 4; ++nt) {
                const float p = __builtin_amdgcn_exp2f(S[nt][r] - mn);
                S[nt][r] = p;
                rs += p;
            }
            rs += __shfl_xor(rs, 1);
            rs += __shfl_xor(rs, 2);
            rs += __shfl_xor(rs, 4);
            rs += __shfl_xor(rs, 8);
            l[r] = l[r] * alpha[r] + rs;
        }
        #pragma unroll
        for (int nt = 0; nt < 4; ++nt)
            #pragma unroll
            for (int r = 0; r < 4; ++r) Oacc[nt][r] *= alpha[r];

        // ---- P: C layout -> bf16 -> wave-private LDS (transpose to A layout)
        #pragma unroll
        for (int nt = 0; nt < 4; ++nt)
            #pragma unroll
            for (int r = 0; r < 4; ++r)
                Ps[w][quad * 4 + r][nt * 16 + col] = f2bf(S[nt][r]);
        __asm__ volatile("s_waitcnt lgkmcnt(0)" ::: "memory");

        // ---- O += P V
        #pragma unroll
        for (int ks = 0; ks < 2; ++ks) {
            bf16x8 ap = *(const bf16x8*)&Ps[w][col][ks * 32 + quad * 8];
            #pragma unroll
            for (int nt = 0; nt < 4; ++nt)
                Oacc[nt] = __builtin_amdgcn_mfma_f32_16x16x32_bf16(ap, vv[ks][nt], Oacc[nt], 0, 0, 0);
        }

        if (more) {                       // rotate prefetch buffer
            #pragma unroll
            for (int nt = 0; nt < 4; ++nt) {
                kc[nt][0] = kn[nt][0];
                kc[nt][1] = kn[nt][1];
            }
        }
    }

    // ---- merge key-halves (kh=1 publishes; kh=0 combines and stores)
    __syncthreads();
    if (kh == 1) {
        #pragma unroll
        for (int nt = 0; nt < 4; ++nt)
            #pragma unroll
            for (int r = 0; r < 4; ++r)
                mO[mt][quad * 4 + r][nt * 16 + col] = Oacc[nt][r];
        if (col == 0) {
            #pragma unroll
            for (int r = 0; r < 4; ++r) {
                mml[0][mt][quad * 4 + r] = m[r];
                mml[1][mt][quad * 4 + r] = l[r];
            }
        }
    }
    __syncthreads();
    if (kh == 0) {
        #pragma unroll
        for (int r = 0; r < 4; ++r) {
            const int row = quad * 4 + r;
            const float m1 = mml[0][mt][row];
            const float l1 = mml[1][mt][row];
            const float ms = fmaxf(m[r], m1);
            const float a0 = __builtin_amdgcn_exp2f(m[r] - ms);
            const float a1 = __builtin_amdgcn_exp2f(m1 - ms);   // -inf -> 0
            const float inv = 1.0f / (a0 * l[r] + a1 * l1);
            float* dst = outp + (size_t)(b * S_ + qbase + row) * H_;
            #pragma unroll
            for (int nt = 0; nt < 4; ++nt)
                dst[nt * 16 + col] =
                    (a0 * Oacc[nt][r] + a1 * mO[mt][row][nt * 16 + col]) * inv;
        }
    }
}

// ---------------------------------------------------------------------------
extern "C" void kernel_launch(void* const* d_in, const int* in_sizes, int n_in,
                              void* d_out, int out_size, void* d_ws, size_t ws_size,
                              hipStream_t stream)
{
    const float* x  = (const float*)d_in[0];
    const float* Wq = (const float*)d_in[1];
    const float* Wk = (const float*)d_in[2];
    const float* Wv = (const float*)d_in[3];
    float* out = (float*)d_out;

    short* Qb = (short*)d_ws;            // [16384][64] bf16   (2 MB)
    short* Kb = Qb + (size_t)BS_ * H_;   // [16384][64] bf16   (2 MB)
    short* Vt = Kb + (size_t)BS_ * H_;   // [8][64][2048] bf16 (2 MB)
    short* Wt = Vt + (size_t)BS_ * H_;   // [3][64][1024] bf16 (384 KB)

    hipLaunchKernelGGL(wprep,    dim3(48), dim3(256), 0, stream, Wq, Wk, Wv, Wt);
    hipLaunchKernelGGL(qkv_proj, dim3(BS_ / 32), dim3(256), 0, stream, x, Wt, Qb, Kb, Vt);
    hipLaunchKernelGGL(attn,     dim3(B_ * (S_ / 32)), dim3(256), 0, stream, Qb, Kb, Vt, out);
}